// Round 2
// baseline (831.976 us; speedup 1.0000x reference)
//
#include <hip/hip_runtime.h>
#include <math.h>

#define N_NODES 50000
#define N_EDGES 1600000
#define N_FEAT  256
#define N_HID   128
#define N_CLASS 64

// ---------------- degree + histogram ----------------
__global__ __launch_bounds__(256) void deg_count_kernel(
    const int* __restrict__ col, const float* __restrict__ ew,
    float* __restrict__ deg, int* __restrict__ counts, int E) {
  int e = blockIdx.x * 256 + threadIdx.x;
  if (e >= E) return;
  int c = col[e];
  atomicAdd(&deg[c], ew[e]);
  atomicAdd(&counts[c], 1);
}

__global__ __launch_bounds__(256) void dinv_kernel(
    const float* __restrict__ deg, float* __restrict__ dinv, int n) {
  int i = blockIdx.x * 256 + threadIdx.x;
  if (i < n) dinv[i] = rsqrtf(deg[i] + 1.0f);  // +1 = self-loop weight; deg>=1 always
}

// ---------------- single-block exclusive scan over counts ----------------
__global__ __launch_bounds__(1024) void scan_kernel(
    const int* __restrict__ counts, int* __restrict__ rowptr, int n) {
  __shared__ int lds[1024];
  __shared__ int carry;
  int tid = threadIdx.x;
  if (tid == 0) carry = 0;
  __syncthreads();
  for (int base = 0; base < n; base += 1024) {
    int i = base + tid;
    int v = (i < n) ? counts[i] : 0;
    lds[tid] = v;
    __syncthreads();
    for (int off = 1; off < 1024; off <<= 1) {
      int t = (tid >= off) ? lds[tid - off] : 0;
      __syncthreads();
      lds[tid] += t;
      __syncthreads();
    }
    int incl  = lds[tid];
    int total = lds[1023];
    int cur   = carry;
    if (i < n) rowptr[i] = cur + incl - v;
    __syncthreads();
    if (tid == 0) carry = cur + total;
    __syncthreads();
  }
  if (tid == 0) rowptr[n] = carry;
}

// ---------------- scatter edges into CSC (sorted by col) ----------------
__global__ __launch_bounds__(256) void scatter_kernel(
    const int* __restrict__ row, const int* __restrict__ col,
    const float* __restrict__ ew, const float* __restrict__ dinv,
    const int* __restrict__ rowptr, int* __restrict__ fill,
    int* __restrict__ erow, float* __restrict__ enorm, int E) {
  int e = blockIdx.x * 256 + threadIdx.x;
  if (e >= E) return;
  int r = row[e], c = col[e];
  float w = dinv[r] * ew[e] * dinv[c];
  int pos = rowptr[c] + atomicAdd(&fill[c], 1);
  erow[pos]  = r;
  enorm[pos] = w;
}

// ---------------- fp32 GEMM: C[M x BN] = A[M x K] @ B[K x BN], full-N blocks ----------------
template <int BN, int BK, int K>
__global__ __launch_bounds__(256) void gemm_kernel(
    const float* __restrict__ A, const float* __restrict__ B,
    float* __restrict__ C, int M) {
  constexpr int BM = 64;
  constexpr int TC = BN / 4;     // threads along cols, 4 cols each
  constexpr int TR = 256 / TC;   // threads along rows
  constexpr int RM = BM / TR;    // rows per thread
  __shared__ float As[BM][BK + 4];
  __shared__ float Bs[BK][BN];

  int t  = threadIdx.x;
  int m0 = blockIdx.x * BM;
  int tc = t % TC, tr = t / TC;

  float acc[RM][4];
#pragma unroll
  for (int r = 0; r < RM; ++r)
#pragma unroll
    for (int c = 0; c < 4; ++c) acc[r][c] = 0.f;

  for (int k0 = 0; k0 < K; k0 += BK) {
    // stage A tile (BM x BK)
    constexpr int F4R = BK / 4;          // float4 per row
#pragma unroll
    for (int p = 0; p < (BM * F4R) / 256; ++p) {
      int row = t / F4R + p * (256 / F4R);
      int c4  = t % F4R;
      int gr  = m0 + row;
      float4 v = make_float4(0.f, 0.f, 0.f, 0.f);
      if (gr < M) v = *(const float4*)&A[(size_t)gr * K + k0 + c4 * 4];
      *(float4*)&As[row][c4 * 4] = v;
    }
    // stage B chunk (BK x BN)
    constexpr int BF4 = BK * BN / 4;
#pragma unroll
    for (int p = 0; p < BF4 / 256; ++p) {
      int idx = p * 256 + t;
      int row = idx / (BN / 4), c4 = idx % (BN / 4);
      *(float4*)&Bs[row][c4 * 4] = *(const float4*)&B[(size_t)(k0 + row) * BN + c4 * 4];
    }
    __syncthreads();

    for (int kk = 0; kk < BK; kk += 4) {
      float4 b0 = *(const float4*)&Bs[kk + 0][tc * 4];
      float4 b1 = *(const float4*)&Bs[kk + 1][tc * 4];
      float4 b2 = *(const float4*)&Bs[kk + 2][tc * 4];
      float4 b3 = *(const float4*)&Bs[kk + 3][tc * 4];
#pragma unroll
      for (int r = 0; r < RM; ++r) {
        float4 a = *(const float4*)&As[tr * RM + r][kk];
        acc[r][0] = fmaf(a.x, b0.x, fmaf(a.y, b1.x, fmaf(a.z, b2.x, fmaf(a.w, b3.x, acc[r][0]))));
        acc[r][1] = fmaf(a.x, b0.y, fmaf(a.y, b1.y, fmaf(a.z, b2.y, fmaf(a.w, b3.y, acc[r][1]))));
        acc[r][2] = fmaf(a.x, b0.z, fmaf(a.y, b1.z, fmaf(a.z, b2.z, fmaf(a.w, b3.z, acc[r][2]))));
        acc[r][3] = fmaf(a.x, b0.w, fmaf(a.y, b1.w, fmaf(a.z, b2.w, fmaf(a.w, b3.w, acc[r][3]))));
      }
    }
    __syncthreads();
  }
#pragma unroll
  for (int r = 0; r < RM; ++r) {
    int gr = m0 + tr * RM + r;
    if (gr < M) {
      float4 v = make_float4(acc[r][0], acc[r][1], acc[r][2], acc[r][3]);
      *(float4*)&C[(size_t)gr * BN + tc * 4] = v;
    }
  }
}

// ---------------- aggregation: out[i] = act( sum_{e in CSC(i)} h[row_e]*norm_e + h[i]*dinv_i^2 + bias ) ----
template <int D, int ACT>  // ACT 0 = sigmoid, 1 = tanh
__global__ __launch_bounds__(256) void agg_kernel(
    const float* __restrict__ h, const int* __restrict__ rowptr,
    const int* __restrict__ erow, const float* __restrict__ enorm,
    const float* __restrict__ dinv, const float* __restrict__ bias,
    float* __restrict__ out, int n) {
  constexpr int PER = D / 64;
  int wid  = (int)((blockIdx.x * blockDim.x + threadIdx.x) >> 6);
  int lane = threadIdx.x & 63;
  if (wid >= n) return;
  int s = rowptr[wid], e_end = rowptr[wid + 1];
  float acc[PER];
#pragma unroll
  for (int p = 0; p < PER; ++p) acc[p] = 0.f;
  for (int e = s; e < e_end; ++e) {
    int r   = erow[e];
    float w = enorm[e];
    const float* hp = h + (size_t)r * D + lane;
#pragma unroll
    for (int p = 0; p < PER; ++p) acc[p] = fmaf(w, hp[p * 64], acc[p]);
  }
  float di = dinv[wid];
  float sw = di * di;
  const float* hp = h + (size_t)wid * D + lane;
#pragma unroll
  for (int p = 0; p < PER; ++p) acc[p] = fmaf(sw, hp[p * 64], acc[p]);
#pragma unroll
  for (int p = 0; p < PER; ++p) {
    float v = acc[p] + bias[lane + p * 64];
    v = (ACT == 0) ? 1.f / (1.f + expf(-v)) : tanhf(v);
    out[(size_t)wid * D + lane + p * 64] = v;
  }
}

extern "C" void kernel_launch(void* const* d_in, const int* in_sizes, int n_in,
                              void* d_out, int out_size, void* d_ws, size_t ws_size,
                              hipStream_t stream) {
  const float* x  = (const float*)d_in[0];
  const int*   ei = (const int*)d_in[1];
  const float* ew = (const float*)d_in[2];
  const float* W1 = (const float*)d_in[3];
  const float* b1 = (const float*)d_in[4];
  const float* W2 = (const float*)d_in[5];
  const float* b2 = (const float*)d_in[6];
  float* out = (float*)d_out;

  const int* row = ei;            // edge_index[0]
  const int* col = ei + N_EDGES;  // edge_index[1]

  char* ws = (char*)d_ws;
  size_t off = 0;
  auto alloc = [&](size_t bytes) {
    void* p = ws + off;
    off = (off + bytes + 255) & ~(size_t)255;
    return p;
  };
  float* deg    = (float*)alloc(N_NODES * 4);
  int*   counts = (int*)alloc(N_NODES * 4);
  int*   fill   = (int*)alloc(N_NODES * 4);
  int*   rowptr = (int*)alloc((N_NODES + 1) * 4);
  float* dinv   = (float*)alloc(N_NODES * 4);
  int*   erow   = (int*)alloc((size_t)N_EDGES * 4);
  float* enorm  = (float*)alloc((size_t)N_EDGES * 4);
  float* bufA   = (float*)alloc((size_t)N_NODES * N_HID * 4);  // h1tmp, then h2tmp
  float* bufB   = (float*)alloc((size_t)N_NODES * N_HID * 4);  // h1

  // zero deg/counts/fill (contiguous span)
  size_t zspan = (size_t)((char*)rowptr - (char*)deg);
  hipMemsetAsync(deg, 0, zspan, stream);

  int eblocks = (N_EDGES + 255) / 256;
  deg_count_kernel<<<eblocks, 256, 0, stream>>>(col, ew, deg, counts, N_EDGES);
  dinv_kernel<<<(N_NODES + 255) / 256, 256, 0, stream>>>(deg, dinv, N_NODES);
  scan_kernel<<<1, 1024, 0, stream>>>(counts, rowptr, N_NODES);
  scatter_kernel<<<eblocks, 256, 0, stream>>>(row, col, ew, dinv, rowptr, fill, erow, enorm, N_EDGES);

  // layer 1: h1 = sigmoid(A @ (x @ W1) + b1)
  gemm_kernel<N_HID, 64, N_FEAT><<<(N_NODES + 63) / 64, 256, 0, stream>>>(x, W1, bufA, N_NODES);
  agg_kernel<N_HID, 0><<<(N_NODES * 64 + 255) / 256, 256, 0, stream>>>(
      bufA, rowptr, erow, enorm, dinv, b1, bufB, N_NODES);

  // layer 2: out = tanh(A @ (h1 @ W2) + b2)
  gemm_kernel<N_CLASS, 64, N_HID><<<(N_NODES + 63) / 64, 256, 0, stream>>>(bufB, W2, bufA, N_NODES);
  agg_kernel<N_CLASS, 1><<<(N_NODES * 64 + 255) / 256, 256, 0, stream>>>(
      bufA, rowptr, erow, enorm, dinv, b2, out, N_NODES);
}

// Round 3
// 558.144 us; speedup vs baseline: 1.4906x; 1.4906x over previous
//
#include <hip/hip_runtime.h>
#include <math.h>

#define N_NODES 50000
#define N_EDGES 1600000
#define N_FEAT  256
#define N_HID   128
#define N_CLASS 64
#define SCAN_NBLK ((N_NODES + 1023) / 1024)

// ---------------- degree + histogram ----------------
__global__ __launch_bounds__(256) void deg_count_kernel(
    const int* __restrict__ col, const float* __restrict__ ew,
    float* __restrict__ deg, int* __restrict__ counts, int E) {
  int e = blockIdx.x * 256 + threadIdx.x;
  if (e >= E) return;
  int c = col[e];
  atomicAdd(&deg[c], ew[e]);
  atomicAdd(&counts[c], 1);
}

__global__ __launch_bounds__(256) void dinv_kernel(
    const float* __restrict__ deg, float* __restrict__ dinv, int n) {
  int i = blockIdx.x * 256 + threadIdx.x;
  if (i < n) dinv[i] = rsqrtf(deg[i] + 1.0f);  // +1 = self-loop weight
}

// ---------------- hierarchical exclusive scan (3 kernels) ----------------
__global__ __launch_bounds__(256) void scan1_kernel(
    const int* __restrict__ counts, int* __restrict__ rowptr,
    int* __restrict__ partials) {
  __shared__ int wsum[4];
  __shared__ int woff[4];
  int t = threadIdx.x, b = blockIdx.x;
  int base = b * 1024 + t * 4;
  int v0 = 0, v1 = 0, v2 = 0, v3 = 0;
  if (base + 3 < N_NODES) {
    int4 v = *(const int4*)&counts[base];
    v0 = v.x; v1 = v.y; v2 = v.z; v3 = v.w;
  } else {
    if (base + 0 < N_NODES) v0 = counts[base + 0];
    if (base + 1 < N_NODES) v1 = counts[base + 1];
    if (base + 2 < N_NODES) v2 = counts[base + 2];
  }
  int s1 = v0 + v1, s2 = s1 + v2, s3 = s2 + v3;
  int lane = t & 63, w = t >> 6;
  int inc = s3;
#pragma unroll
  for (int off = 1; off < 64; off <<= 1) {
    int u = __shfl_up(inc, off, 64);
    if (lane >= off) inc += u;
  }
  if (lane == 63) wsum[w] = inc;
  __syncthreads();
  if (t == 0) {
    int a = 0;
#pragma unroll
    for (int i = 0; i < 4; ++i) { woff[i] = a; a += wsum[i]; }
    partials[b] = a;
  }
  __syncthreads();
  int ex = woff[w] + inc - s3;  // exclusive prefix before this thread (in block)
  if (base + 0 < N_NODES) rowptr[base + 0] = ex;
  if (base + 1 < N_NODES) rowptr[base + 1] = ex + v0;
  if (base + 2 < N_NODES) rowptr[base + 2] = ex + s1;
  if (base + 3 < N_NODES) rowptr[base + 3] = ex + s2;
}

__global__ void scan2_kernel(int* __restrict__ partials, int* __restrict__ rowptr) {
  if (threadIdx.x == 0 && blockIdx.x == 0) {
    int a = 0;
    for (int i = 0; i < SCAN_NBLK; ++i) { int x = partials[i]; partials[i] = a; a += x; }
    rowptr[N_NODES] = a;  // == N_EDGES
  }
}

__global__ __launch_bounds__(256) void scan3_kernel(
    int* __restrict__ rowptr, const int* __restrict__ partials) {
  int i = blockIdx.x * 256 + threadIdx.x;
  if (i < N_NODES) rowptr[i] += partials[i >> 10];
}

// ---------------- scatter edges into CSC (sorted by col), packed (row, norm) ----
__global__ __launch_bounds__(256) void scatter_kernel(
    const int* __restrict__ row, const int* __restrict__ col,
    const float* __restrict__ ew, const float* __restrict__ dinv,
    const int* __restrict__ rowptr, int* __restrict__ fill,
    int2* __restrict__ ep, int E) {
  int e = blockIdx.x * 256 + threadIdx.x;
  if (e >= E) return;
  int r = row[e], c = col[e];
  float w = dinv[r] * ew[e] * dinv[c];
  int pos = rowptr[c] + atomicAdd(&fill[c], 1);
  ep[pos] = make_int2(r, __float_as_int(w));
}

// ---------------- fp32 GEMM with bf16 output: C[M x BN] = A[M x K] @ B[K x BN] ----
__device__ __forceinline__ unsigned short f2bf(float f) {
  unsigned int u = __float_as_uint(f);
  unsigned int r = (u + 0x7fffu + ((u >> 16) & 1u)) >> 16;  // RNE
  return (unsigned short)r;
}

template <int BN, int BK, int K>
__global__ __launch_bounds__(256) void gemm_kernel(
    const float* __restrict__ A, const float* __restrict__ B,
    unsigned short* __restrict__ C, int M) {
  constexpr int BM = 64;
  constexpr int TC = BN / 4;     // threads along cols, 4 cols each
  constexpr int TR = 256 / TC;   // threads along rows
  constexpr int RM = BM / TR;    // rows per thread
  __shared__ float As[BM][BK + 4];
  __shared__ float Bs[BK][BN];

  int t  = threadIdx.x;
  int m0 = blockIdx.x * BM;
  int tc = t % TC, tr = t / TC;

  float acc[RM][4];
#pragma unroll
  for (int r = 0; r < RM; ++r)
#pragma unroll
    for (int c = 0; c < 4; ++c) acc[r][c] = 0.f;

  for (int k0 = 0; k0 < K; k0 += BK) {
    constexpr int F4R = BK / 4;
#pragma unroll
    for (int p = 0; p < (BM * F4R) / 256; ++p) {
      int row = t / F4R + p * (256 / F4R);
      int c4  = t % F4R;
      int gr  = m0 + row;
      float4 v = make_float4(0.f, 0.f, 0.f, 0.f);
      if (gr < M) v = *(const float4*)&A[(size_t)gr * K + k0 + c4 * 4];
      *(float4*)&As[row][c4 * 4] = v;
    }
    constexpr int BF4 = BK * BN / 4;
#pragma unroll
    for (int p = 0; p < BF4 / 256; ++p) {
      int idx = p * 256 + t;
      int row = idx / (BN / 4), c4 = idx % (BN / 4);
      *(float4*)&Bs[row][c4 * 4] = *(const float4*)&B[(size_t)(k0 + row) * BN + c4 * 4];
    }
    __syncthreads();

    for (int kk = 0; kk < BK; kk += 4) {
      float4 b0 = *(const float4*)&Bs[kk + 0][tc * 4];
      float4 b1 = *(const float4*)&Bs[kk + 1][tc * 4];
      float4 b2 = *(const float4*)&Bs[kk + 2][tc * 4];
      float4 b3 = *(const float4*)&Bs[kk + 3][tc * 4];
#pragma unroll
      for (int r = 0; r < RM; ++r) {
        float4 a = *(const float4*)&As[tr * RM + r][kk];
        acc[r][0] = fmaf(a.x, b0.x, fmaf(a.y, b1.x, fmaf(a.z, b2.x, fmaf(a.w, b3.x, acc[r][0]))));
        acc[r][1] = fmaf(a.x, b0.y, fmaf(a.y, b1.y, fmaf(a.z, b2.y, fmaf(a.w, b3.y, acc[r][1]))));
        acc[r][2] = fmaf(a.x, b0.z, fmaf(a.y, b1.z, fmaf(a.z, b2.z, fmaf(a.w, b3.z, acc[r][2]))));
        acc[r][3] = fmaf(a.x, b0.w, fmaf(a.y, b1.w, fmaf(a.z, b2.w, fmaf(a.w, b3.w, acc[r][3]))));
      }
    }
    __syncthreads();
  }
#pragma unroll
  for (int r = 0; r < RM; ++r) {
    int gr = m0 + tr * RM + r;
    if (gr < M) {
      uint2 o;
      o.x = (unsigned int)f2bf(acc[r][0]) | ((unsigned int)f2bf(acc[r][1]) << 16);
      o.y = (unsigned int)f2bf(acc[r][2]) | ((unsigned int)f2bf(acc[r][3]) << 16);
      *(uint2*)&C[(size_t)gr * BN + tc * 4] = o;
    }
  }
}

// ---------------- aggregation D=128: wave per node, lane owns features (2l, 2l+1) ----
__global__ __launch_bounds__(256) void agg128_kernel(
    const unsigned short* __restrict__ h, const int* __restrict__ rowptr,
    const int2* __restrict__ ep, const float* __restrict__ dinv,
    const float* __restrict__ bias, float* __restrict__ out, int n) {
  int wid  = (int)((blockIdx.x * 256 + threadIdx.x) >> 6);
  int lane = threadIdx.x & 63;
  if (wid >= n) return;
  int s = rowptr[wid], e_end = rowptr[wid + 1];
  unsigned int f2 = 2u * lane;
  float a0 = 0.f, a1 = 0.f, b0 = 0.f, b1 = 0.f;
  int e = s;
  for (; e + 1 < e_end; e += 2) {
    int2 p0 = ep[e], p1 = ep[e + 1];
    unsigned int h0 = *(const unsigned int*)(h + ((size_t)p0.x << 7) + f2);
    unsigned int h1 = *(const unsigned int*)(h + ((size_t)p1.x << 7) + f2);
    float w0 = __int_as_float(p0.y), w1 = __int_as_float(p1.y);
    a0 = fmaf(w0, __uint_as_float(h0 << 16), a0);
    a1 = fmaf(w0, __uint_as_float(h0 & 0xffff0000u), a1);
    b0 = fmaf(w1, __uint_as_float(h1 << 16), b0);
    b1 = fmaf(w1, __uint_as_float(h1 & 0xffff0000u), b1);
  }
  if (e < e_end) {
    int2 p0 = ep[e];
    unsigned int h0 = *(const unsigned int*)(h + ((size_t)p0.x << 7) + f2);
    float w0 = __int_as_float(p0.y);
    a0 = fmaf(w0, __uint_as_float(h0 << 16), a0);
    a1 = fmaf(w0, __uint_as_float(h0 & 0xffff0000u), a1);
  }
  float di = dinv[wid], sw = di * di;
  unsigned int hs = *(const unsigned int*)(h + ((size_t)wid << 7) + f2);
  a0 = fmaf(sw, __uint_as_float(hs << 16), a0);
  a1 = fmaf(sw, __uint_as_float(hs & 0xffff0000u), a1);
  float v0 = a0 + b0 + bias[f2];
  float v1 = a1 + b1 + bias[f2 + 1];
  v0 = 1.f / (1.f + expf(-v0));  // sigmoid
  v1 = 1.f / (1.f + expf(-v1));
  *(float2*)&out[((size_t)wid << 7) + f2] = make_float2(v0, v1);
}

// ---------------- aggregation D=64: wave per node, lane-halves process 2 edges ----
__global__ __launch_bounds__(256) void agg64_kernel(
    const unsigned short* __restrict__ h, const int* __restrict__ rowptr,
    const int2* __restrict__ ep, const float* __restrict__ dinv,
    const float* __restrict__ bias, float* __restrict__ out, int n) {
  int wid  = (int)((blockIdx.x * 256 + threadIdx.x) >> 6);
  int lane = threadIdx.x & 63;
  if (wid >= n) return;
  int half = lane >> 5, ll = lane & 31;
  unsigned int f2 = 2u * ll;
  int s = rowptr[wid], e_end = rowptr[wid + 1];
  float a0 = 0.f, a1 = 0.f, b0 = 0.f, b1 = 0.f;
  int e = s + half;
  for (; e + 2 < e_end; e += 4) {
    int2 p0 = ep[e], p1 = ep[e + 2];
    unsigned int h0 = *(const unsigned int*)(h + ((size_t)p0.x << 6) + f2);
    unsigned int h1 = *(const unsigned int*)(h + ((size_t)p1.x << 6) + f2);
    float w0 = __int_as_float(p0.y), w1 = __int_as_float(p1.y);
    a0 = fmaf(w0, __uint_as_float(h0 << 16), a0);
    a1 = fmaf(w0, __uint_as_float(h0 & 0xffff0000u), a1);
    b0 = fmaf(w1, __uint_as_float(h1 << 16), b0);
    b1 = fmaf(w1, __uint_as_float(h1 & 0xffff0000u), b1);
  }
  if (e < e_end) {
    int2 p0 = ep[e];
    unsigned int h0 = *(const unsigned int*)(h + ((size_t)p0.x << 6) + f2);
    float w0 = __int_as_float(p0.y);
    a0 = fmaf(w0, __uint_as_float(h0 << 16), a0);
    a1 = fmaf(w0, __uint_as_float(h0 & 0xffff0000u), a1);
  }
  a0 += b0; a1 += b1;
  if (half == 0) {  // self-loop term exactly once
    float di = dinv[wid], sw = di * di;
    unsigned int hs = *(const unsigned int*)(h + ((size_t)wid << 6) + f2);
    a0 = fmaf(sw, __uint_as_float(hs << 16), a0);
    a1 = fmaf(sw, __uint_as_float(hs & 0xffff0000u), a1);
  }
  a0 += __shfl_xor(a0, 32, 64);
  a1 += __shfl_xor(a1, 32, 64);
  if (half == 0) {
    float v0 = tanhf(a0 + bias[f2]);
    float v1 = tanhf(a1 + bias[f2 + 1]);
    *(float2*)&out[(size_t)wid * 64 + f2] = make_float2(v0, v1);
  }
}

extern "C" void kernel_launch(void* const* d_in, const int* in_sizes, int n_in,
                              void* d_out, int out_size, void* d_ws, size_t ws_size,
                              hipStream_t stream) {
  const float* x  = (const float*)d_in[0];
  const int*   ei = (const int*)d_in[1];
  const float* ew = (const float*)d_in[2];
  const float* W1 = (const float*)d_in[3];
  const float* b1 = (const float*)d_in[4];
  const float* W2 = (const float*)d_in[5];
  const float* b2 = (const float*)d_in[6];
  float* out = (float*)d_out;

  const int* row = ei;            // edge_index[0]
  const int* col = ei + N_EDGES;  // edge_index[1]

  char* ws = (char*)d_ws;
  size_t off = 0;
  auto alloc = [&](size_t bytes) {
    void* p = ws + off;
    off = (off + bytes + 255) & ~(size_t)255;
    return p;
  };
  float* deg      = (float*)alloc(N_NODES * 4);
  int*   counts   = (int*)alloc(N_NODES * 4);
  int*   fill     = (int*)alloc(N_NODES * 4);
  int*   rowptr   = (int*)alloc((N_NODES + 1) * 4);
  float* dinv     = (float*)alloc(N_NODES * 4);
  int*   partials = (int*)alloc(SCAN_NBLK * 4);
  int2*  ep       = (int2*)alloc((size_t)N_EDGES * 8);
  unsigned short* bufA = (unsigned short*)alloc((size_t)N_NODES * N_HID * 2);   // bf16 x@W1
  float*          bufB = (float*)alloc((size_t)N_NODES * N_HID * 4);            // fp32 h1
  unsigned short* bufC = (unsigned short*)alloc((size_t)N_NODES * N_CLASS * 2); // bf16 h1@W2

  // zero deg/counts/fill (contiguous span)
  size_t zspan = (size_t)((char*)rowptr - (char*)deg);
  hipMemsetAsync(deg, 0, zspan, stream);

  int eblocks = (N_EDGES + 255) / 256;
  int nblocks = (N_NODES + 255) / 256;
  deg_count_kernel<<<eblocks, 256, 0, stream>>>(col, ew, deg, counts, N_EDGES);
  dinv_kernel<<<nblocks, 256, 0, stream>>>(deg, dinv, N_NODES);
  scan1_kernel<<<SCAN_NBLK, 256, 0, stream>>>(counts, rowptr, partials);
  scan2_kernel<<<1, 64, 0, stream>>>(partials, rowptr);
  scan3_kernel<<<nblocks, 256, 0, stream>>>(rowptr, partials);
  scatter_kernel<<<eblocks, 256, 0, stream>>>(row, col, ew, dinv, rowptr, fill, ep, N_EDGES);

  // layer 1: h1 = sigmoid(A @ (x @ W1) + b1)
  gemm_kernel<N_HID, 64, N_FEAT><<<(N_NODES + 63) / 64, 256, 0, stream>>>(x, W1, bufA, N_NODES);
  agg128_kernel<<<(N_NODES * 64 + 255) / 256, 256, 0, stream>>>(
      bufA, rowptr, ep, dinv, b1, bufB, N_NODES);

  // layer 2: out = tanh(A @ (h1 @ W2) + b2)
  gemm_kernel<N_CLASS, 64, N_HID><<<(N_NODES + 63) / 64, 256, 0, stream>>>(bufB, W2, bufC, N_NODES);
  agg64_kernel<<<(N_NODES * 64 + 255) / 256, 256, 0, stream>>>(
      bufC, rowptr, ep, dinv, b2, out, N_NODES);
}

// Round 4
// 438.459 us; speedup vs baseline: 1.8975x; 1.2730x over previous
//
#include <hip/hip_runtime.h>
#include <math.h>

#define N_NODES 50000
#define N_EDGES 1600000
#define N_FEAT  256
#define N_HID   128
#define N_CLASS 64
#define SCAN_NBLK ((N_NODES + 1023) / 1024)
#define FIXSCALE 268435456.0f  // 2^28

// ---------------- pass A: packed degree/count histogram + per-edge rank ----------------
__global__ __launch_bounds__(256) void deg_rank_kernel(
    const int* __restrict__ col, const float* __restrict__ ew,
    unsigned long long* __restrict__ packed, unsigned short* __restrict__ rank, int E) {
  int e = blockIdx.x * 256 + threadIdx.x;
  if (e >= E) return;
  int c = col[e];
  unsigned long long fix = (unsigned long long)__float2uint_rn(ew[e] * FIXSCALE);
  unsigned long long old = atomicAdd(&packed[c], (1ULL << 40) | fix);
  rank[e] = (unsigned short)(old >> 40);
}

__global__ __launch_bounds__(256) void unpack_kernel(
    const unsigned long long* __restrict__ packed, int* __restrict__ counts,
    float* __restrict__ dinv, int n) {
  int i = blockIdx.x * 256 + threadIdx.x;
  if (i >= n) return;
  unsigned long long p = packed[i];
  counts[i] = (int)(p >> 40);
  float deg = (float)(long long)(p & 0xFFFFFFFFFFULL) * (1.0f / FIXSCALE);
  dinv[i] = rsqrtf(deg + 1.0f);  // +1 = self-loop weight
}

// ---------------- hierarchical exclusive scan (3 kernels) ----------------
__global__ __launch_bounds__(256) void scan1_kernel(
    const int* __restrict__ counts, int* __restrict__ rowptr,
    int* __restrict__ partials) {
  __shared__ int wsum[4];
  __shared__ int woff[4];
  int t = threadIdx.x, b = blockIdx.x;
  int base = b * 1024 + t * 4;
  int v0 = 0, v1 = 0, v2 = 0, v3 = 0;
  if (base + 3 < N_NODES) {
    int4 v = *(const int4*)&counts[base];
    v0 = v.x; v1 = v.y; v2 = v.z; v3 = v.w;
  } else {
    if (base + 0 < N_NODES) v0 = counts[base + 0];
    if (base + 1 < N_NODES) v1 = counts[base + 1];
    if (base + 2 < N_NODES) v2 = counts[base + 2];
  }
  int s1 = v0 + v1, s2 = s1 + v2, s3 = s2 + v3;
  int lane = t & 63, w = t >> 6;
  int inc = s3;
#pragma unroll
  for (int off = 1; off < 64; off <<= 1) {
    int u = __shfl_up(inc, off, 64);
    if (lane >= off) inc += u;
  }
  if (lane == 63) wsum[w] = inc;
  __syncthreads();
  if (t == 0) {
    int a = 0;
#pragma unroll
    for (int i = 0; i < 4; ++i) { woff[i] = a; a += wsum[i]; }
    partials[b] = a;
  }
  __syncthreads();
  int ex = woff[w] + inc - s3;  // exclusive prefix before this thread (in block)
  if (base + 0 < N_NODES) rowptr[base + 0] = ex;
  if (base + 1 < N_NODES) rowptr[base + 1] = ex + v0;
  if (base + 2 < N_NODES) rowptr[base + 2] = ex + s1;
  if (base + 3 < N_NODES) rowptr[base + 3] = ex + s2;
}

__global__ void scan2_kernel(int* __restrict__ partials, int* __restrict__ rowptr) {
  if (threadIdx.x == 0 && blockIdx.x == 0) {
    int a = 0;
    for (int i = 0; i < SCAN_NBLK; ++i) { int x = partials[i]; partials[i] = a; a += x; }
    rowptr[N_NODES] = a;  // == N_EDGES
  }
}

__global__ __launch_bounds__(256) void scan3_kernel(
    int* __restrict__ rowptr, const int* __restrict__ partials) {
  int i = blockIdx.x * 256 + threadIdx.x;
  if (i < N_NODES) rowptr[i] += partials[i >> 10];
}

// ---------------- pass B: atomic-free scatter into CSC ----------------
__global__ __launch_bounds__(256) void scatter_kernel(
    const int* __restrict__ row, const int* __restrict__ col,
    const float* __restrict__ ew, const unsigned short* __restrict__ rank,
    const float* __restrict__ dinv, const int* __restrict__ rowptr,
    int2* __restrict__ ep, int E) {
  int e = blockIdx.x * 256 + threadIdx.x;
  if (e >= E) return;
  int r = row[e], c = col[e];
  float w = dinv[r] * ew[e] * dinv[c];
  int pos = rowptr[c] + (int)rank[e];
  ep[pos] = make_int2(r, __float_as_int(w));
}

// ---------------- fp32 GEMM with bf16 output: C[M x BN] = A[M x K] @ B[K x BN] ----
__device__ __forceinline__ unsigned short f2bf(float f) {
  unsigned int u = __float_as_uint(f);
  unsigned int r = (u + 0x7fffu + ((u >> 16) & 1u)) >> 16;  // RNE
  return (unsigned short)r;
}

template <int BN, int BK, int K>
__global__ __launch_bounds__(256) void gemm_kernel(
    const float* __restrict__ A, const float* __restrict__ B,
    unsigned short* __restrict__ C, int M) {
  constexpr int BM = 64;
  constexpr int TC = BN / 4;     // threads along cols, 4 cols each
  constexpr int TR = 256 / TC;   // threads along rows
  constexpr int RM = BM / TR;    // rows per thread
  __shared__ float As[BM][BK + 4];
  __shared__ float Bs[BK][BN];

  int t  = threadIdx.x;
  int m0 = blockIdx.x * BM;
  int tc = t % TC, tr = t / TC;

  float acc[RM][4];
#pragma unroll
  for (int r = 0; r < RM; ++r)
#pragma unroll
    for (int c = 0; c < 4; ++c) acc[r][c] = 0.f;

  for (int k0 = 0; k0 < K; k0 += BK) {
    constexpr int F4R = BK / 4;
#pragma unroll
    for (int p = 0; p < (BM * F4R) / 256; ++p) {
      int row = t / F4R + p * (256 / F4R);
      int c4  = t % F4R;
      int gr  = m0 + row;
      float4 v = make_float4(0.f, 0.f, 0.f, 0.f);
      if (gr < M) v = *(const float4*)&A[(size_t)gr * K + k0 + c4 * 4];
      *(float4*)&As[row][c4 * 4] = v;
    }
    constexpr int BF4 = BK * BN / 4;
#pragma unroll
    for (int p = 0; p < BF4 / 256; ++p) {
      int idx = p * 256 + t;
      int row = idx / (BN / 4), c4 = idx % (BN / 4);
      *(float4*)&Bs[row][c4 * 4] = *(const float4*)&B[(size_t)(k0 + row) * BN + c4 * 4];
    }
    __syncthreads();

    for (int kk = 0; kk < BK; kk += 4) {
      float4 b0 = *(const float4*)&Bs[kk + 0][tc * 4];
      float4 b1 = *(const float4*)&Bs[kk + 1][tc * 4];
      float4 b2 = *(const float4*)&Bs[kk + 2][tc * 4];
      float4 b3 = *(const float4*)&Bs[kk + 3][tc * 4];
#pragma unroll
      for (int r = 0; r < RM; ++r) {
        float4 a = *(const float4*)&As[tr * RM + r][kk];
        acc[r][0] = fmaf(a.x, b0.x, fmaf(a.y, b1.x, fmaf(a.z, b2.x, fmaf(a.w, b3.x, acc[r][0]))));
        acc[r][1] = fmaf(a.x, b0.y, fmaf(a.y, b1.y, fmaf(a.z, b2.y, fmaf(a.w, b3.y, acc[r][1]))));
        acc[r][2] = fmaf(a.x, b0.z, fmaf(a.y, b1.z, fmaf(a.z, b2.z, fmaf(a.w, b3.z, acc[r][2]))));
        acc[r][3] = fmaf(a.x, b0.w, fmaf(a.y, b1.w, fmaf(a.z, b2.w, fmaf(a.w, b3.w, acc[r][3]))));
      }
    }
    __syncthreads();
  }
#pragma unroll
  for (int r = 0; r < RM; ++r) {
    int gr = m0 + tr * RM + r;
    if (gr < M) {
      uint2 o;
      o.x = (unsigned int)f2bf(acc[r][0]) | ((unsigned int)f2bf(acc[r][1]) << 16);
      o.y = (unsigned int)f2bf(acc[r][2]) | ((unsigned int)f2bf(acc[r][3]) << 16);
      *(uint2*)&C[(size_t)gr * BN + tc * 4] = o;
    }
  }
}

// ---------------- aggregation D=128: wave per node, lane owns features (2l, 2l+1) ----
__global__ __launch_bounds__(256) void agg128_kernel(
    const unsigned short* __restrict__ h, const int* __restrict__ rowptr,
    const int2* __restrict__ ep, const float* __restrict__ dinv,
    const float* __restrict__ bias, float* __restrict__ out, int n) {
  int wid  = (int)((blockIdx.x * 256 + threadIdx.x) >> 6);
  int lane = threadIdx.x & 63;
  if (wid >= n) return;
  int s = rowptr[wid], e_end = rowptr[wid + 1];
  unsigned int f2 = 2u * lane;
  float a0 = 0.f, a1 = 0.f, b0 = 0.f, b1 = 0.f;
  int e = s;
  for (; e + 1 < e_end; e += 2) {
    int2 p0 = ep[e], p1 = ep[e + 1];
    unsigned int h0 = *(const unsigned int*)(h + ((size_t)p0.x << 7) + f2);
    unsigned int h1 = *(const unsigned int*)(h + ((size_t)p1.x << 7) + f2);
    float w0 = __int_as_float(p0.y), w1 = __int_as_float(p1.y);
    a0 = fmaf(w0, __uint_as_float(h0 << 16), a0);
    a1 = fmaf(w0, __uint_as_float(h0 & 0xffff0000u), a1);
    b0 = fmaf(w1, __uint_as_float(h1 << 16), b0);
    b1 = fmaf(w1, __uint_as_float(h1 & 0xffff0000u), b1);
  }
  if (e < e_end) {
    int2 p0 = ep[e];
    unsigned int h0 = *(const unsigned int*)(h + ((size_t)p0.x << 7) + f2);
    float w0 = __int_as_float(p0.y);
    a0 = fmaf(w0, __uint_as_float(h0 << 16), a0);
    a1 = fmaf(w0, __uint_as_float(h0 & 0xffff0000u), a1);
  }
  float di = dinv[wid], sw = di * di;
  unsigned int hs = *(const unsigned int*)(h + ((size_t)wid << 7) + f2);
  a0 = fmaf(sw, __uint_as_float(hs << 16), a0);
  a1 = fmaf(sw, __uint_as_float(hs & 0xffff0000u), a1);
  float v0 = a0 + b0 + bias[f2];
  float v1 = a1 + b1 + bias[f2 + 1];
  v0 = 1.f / (1.f + expf(-v0));  // sigmoid
  v1 = 1.f / (1.f + expf(-v1));
  *(float2*)&out[((size_t)wid << 7) + f2] = make_float2(v0, v1);
}

// ---------------- aggregation D=64: wave per node, lane-halves process 2 edges ----
__global__ __launch_bounds__(256) void agg64_kernel(
    const unsigned short* __restrict__ h, const int* __restrict__ rowptr,
    const int2* __restrict__ ep, const float* __restrict__ dinv,
    const float* __restrict__ bias, float* __restrict__ out, int n) {
  int wid  = (int)((blockIdx.x * 256 + threadIdx.x) >> 6);
  int lane = threadIdx.x & 63;
  if (wid >= n) return;
  int half = lane >> 5, ll = lane & 31;
  unsigned int f2 = 2u * ll;
  int s = rowptr[wid], e_end = rowptr[wid + 1];
  float a0 = 0.f, a1 = 0.f, b0 = 0.f, b1 = 0.f;
  int e = s + half;
  for (; e + 2 < e_end; e += 4) {
    int2 p0 = ep[e], p1 = ep[e + 2];
    unsigned int h0 = *(const unsigned int*)(h + ((size_t)p0.x << 6) + f2);
    unsigned int h1 = *(const unsigned int*)(h + ((size_t)p1.x << 6) + f2);
    float w0 = __int_as_float(p0.y), w1 = __int_as_float(p1.y);
    a0 = fmaf(w0, __uint_as_float(h0 << 16), a0);
    a1 = fmaf(w0, __uint_as_float(h0 & 0xffff0000u), a1);
    b0 = fmaf(w1, __uint_as_float(h1 << 16), b0);
    b1 = fmaf(w1, __uint_as_float(h1 & 0xffff0000u), b1);
  }
  if (e < e_end) {
    int2 p0 = ep[e];
    unsigned int h0 = *(const unsigned int*)(h + ((size_t)p0.x << 6) + f2);
    float w0 = __int_as_float(p0.y);
    a0 = fmaf(w0, __uint_as_float(h0 << 16), a0);
    a1 = fmaf(w0, __uint_as_float(h0 & 0xffff0000u), a1);
  }
  a0 += b0; a1 += b1;
  if (half == 0) {  // self-loop term exactly once
    float di = dinv[wid], sw = di * di;
    unsigned int hs = *(const unsigned int*)(h + ((size_t)wid << 6) + f2);
    a0 = fmaf(sw, __uint_as_float(hs << 16), a0);
    a1 = fmaf(sw, __uint_as_float(hs & 0xffff0000u), a1);
  }
  a0 += __shfl_xor(a0, 32, 64);
  a1 += __shfl_xor(a1, 32, 64);
  if (half == 0) {
    float v0 = tanhf(a0 + bias[f2]);
    float v1 = tanhf(a1 + bias[f2 + 1]);
    *(float2*)&out[(size_t)wid * 64 + f2] = make_float2(v0, v1);
  }
}

extern "C" void kernel_launch(void* const* d_in, const int* in_sizes, int n_in,
                              void* d_out, int out_size, void* d_ws, size_t ws_size,
                              hipStream_t stream) {
  const float* x  = (const float*)d_in[0];
  const int*   ei = (const int*)d_in[1];
  const float* ew = (const float*)d_in[2];
  const float* W1 = (const float*)d_in[3];
  const float* b1 = (const float*)d_in[4];
  const float* W2 = (const float*)d_in[5];
  const float* b2 = (const float*)d_in[6];
  float* out = (float*)d_out;

  const int* row = ei;            // edge_index[0]
  const int* col = ei + N_EDGES;  // edge_index[1]

  char* ws = (char*)d_ws;
  size_t off = 0;
  auto alloc = [&](size_t bytes) {
    void* p = ws + off;
    off = (off + bytes + 255) & ~(size_t)255;
    return p;
  };
  unsigned long long* packed = (unsigned long long*)alloc(N_NODES * 8);
  int*   counts   = (int*)alloc(N_NODES * 4);
  int*   rowptr   = (int*)alloc((N_NODES + 1) * 4);
  float* dinv     = (float*)alloc(N_NODES * 4);
  int*   partials = (int*)alloc(SCAN_NBLK * 4);
  unsigned short* rank = (unsigned short*)alloc((size_t)N_EDGES * 2);
  int2*  ep       = (int2*)alloc((size_t)N_EDGES * 8);
  unsigned short* bufA = (unsigned short*)alloc((size_t)N_NODES * N_HID * 2);   // bf16 x@W1
  float*          bufB = (float*)alloc((size_t)N_NODES * N_HID * 4);            // fp32 h1
  unsigned short* bufC = (unsigned short*)alloc((size_t)N_NODES * N_CLASS * 2); // bf16 h1@W2

  hipMemsetAsync(packed, 0, N_NODES * 8, stream);

  int eblocks = (N_EDGES + 255) / 256;
  int nblocks = (N_NODES + 255) / 256;
  deg_rank_kernel<<<eblocks, 256, 0, stream>>>(col, ew, packed, rank, N_EDGES);
  unpack_kernel<<<nblocks, 256, 0, stream>>>(packed, counts, dinv, N_NODES);
  scan1_kernel<<<SCAN_NBLK, 256, 0, stream>>>(counts, rowptr, partials);
  scan2_kernel<<<1, 64, 0, stream>>>(partials, rowptr);
  scan3_kernel<<<nblocks, 256, 0, stream>>>(rowptr, partials);
  scatter_kernel<<<eblocks, 256, 0, stream>>>(row, col, ew, rank, dinv, rowptr, ep, N_EDGES);

  // layer 1: h1 = sigmoid(A @ (x @ W1) + b1)
  gemm_kernel<N_HID, 64, N_FEAT><<<(N_NODES + 63) / 64, 256, 0, stream>>>(x, W1, bufA, N_NODES);
  agg128_kernel<<<(N_NODES * 64 + 255) / 256, 256, 0, stream>>>(
      bufA, rowptr, ep, dinv, b1, bufB, N_NODES);

  // layer 2: out = tanh(A @ (h1 @ W2) + b2)
  gemm_kernel<N_CLASS, 64, N_HID><<<(N_NODES + 63) / 64, 256, 0, stream>>>(bufB, W2, bufC, N_NODES);
  agg64_kernel<<<(N_NODES * 64 + 255) / 256, 256, 0, stream>>>(
      bufC, rowptr, ep, dinv, b2, out, N_NODES);
}